// Round 20
// baseline (60.980 us; speedup 1.0000x reference)
//
#include <hip/hip_runtime.h>
#include <hip/hip_bf16.h>

#define B_    4096
#define D_    512         // elements = bytes per row (i8)
#define TB_   8192        // 2B rows
#define BM    128
#define BK    256         // 256 B per row per K-tile -> only 2 drain events
#define NK    2           // D_/BK
#define NTILE 64          // TB_/BM
#define NTRI  2080        // NTILE*(NTILE+1)/2 = 8*260 (XCD-bijective)
#define INV_T 14.285714285714286f   // 1/0.07
#define SCL   (INV_T / 16129.0f)    // 1/(0.07*127*127)

typedef __attribute__((ext_vector_type(4))) int v4i;

#define GLOAD_LDS16(gp, lp)                                                        \
  __builtin_amdgcn_global_load_lds((const __attribute__((address_space(1))) void*)(gp), \
                                   (__attribute__((address_space(3))) void*)(lp),  \
                                   16, 0, 0)

// ---------------------------------------------------------------------------
// Kernel 1: concat + quantize fp32 -> int8 (E8[8192][512], q = rn(127 x)).
// ---------------------------------------------------------------------------
__global__ void ntx_prep(const float* __restrict__ a, const float* __restrict__ b,
                         char* __restrict__ E8) {
  int t = blockIdx.x * blockDim.x + threadIdx.x;      // 0..262143
  int i = t * 16;
  const float* src = (i < B_ * D_) ? (a + i) : (b + (i - B_ * D_));
  v4i o;
#pragma unroll
  for (int g = 0; g < 4; ++g) {
    float4 v = ((const float4*)src)[g];
    int q0 = __float2int_rn(v.x * 127.0f) & 255;
    int q1 = __float2int_rn(v.y * 127.0f) & 255;
    int q2 = __float2int_rn(v.z * 127.0f) & 255;
    int q3 = __float2int_rn(v.w * 127.0f) & 255;
    o[g] = q0 | (q1 << 8) | (q2 << 16) | (q3 << 24);
  }
  ((v4i*)E8)[t] = o;
}

// ---------------------------------------------------------------------------
// Kernel 2: R17's i8 GEMM with BK=256 / NK=2 — halves the per-block
// stage-drain events (4 -> 2), the only lever with measured positive slope
// (R9: 8 -> 4 phases = -4.5 us). LDS 64 KB (A 32 + B 32) -> 2 blocks/CU.
// Swizzle ledger at 256 B rows: 16 chunks(16B)/row, chunk ^= row&7
// (bits 0-2 only -> bijective); bank-quad spread = 8, 2-way = free.
// Staging: 2048 chunks/matrix, 8 rounds x 256 thr; round advances 16 rows
// (==0 mod 8) so swizzle col is round-invariant (R17 algebra).
// Frag chunk col = ks*4 + lhi, ks = 0..3. Epilogue/P-slots: R17-verified.
// ---------------------------------------------------------------------------
__global__ __launch_bounds__(256, 2)
void ntx_sim(const char* __restrict__ E8, float* __restrict__ P,
             float* __restrict__ pos) {
  __shared__ __align__(16) char As[BM * BK];   // 32 KB
  __shared__ __align__(16) char Bs[BM * BK];   // 32 KB

  // XCD-contiguous bijective swizzle (2080 = 8*260)
  const int bid = blockIdx.x;
  const int t   = (bid & 7) * (NTRI / 8) + (bid >> 3);
  // decode triangular index t -> (ti, tj), ti<=tj
  int ti = (int)((129.0f - sqrtf(16641.0f - 8.0f * (float)t)) * 0.5f);
  while (ti * (129 - ti) / 2 > t) --ti;
  while ((ti + 1) * (128 - ti) / 2 <= t) ++ti;
  const int tj = ti + (t - ti * (129 - ti) / 2);
  const int rowTile = ti * BM, colTile = tj * BM;
  const bool diag = (ti == tj);
  const bool posT = (tj == ti + B_ / BM);   // holds s[r][r+B] on local diag

  const int tid = threadIdx.x, lane = tid & 63, wave = tid >> 6;
  const int wr = wave >> 1, wc = wave & 1;
  const int llo = lane & 15, lhi = lane >> 4;

  // --- staging bases: chunk = r*256 + tid; row = chunk>>4; col = chunk&15.
  // round r: +16 rows (8192 B global, 4096 B LDS); swizzle col invariant.
  const int srow = tid >> 4;
  const int scol = tid & 15;
  const int ssc  = ((scol ^ (srow & 7)) << 4);
  const unsigned offA0  = (unsigned)(rowTile + srow) * D_ + ssc;
  const unsigned offB0  = (unsigned)(colTile + srow) * D_ + ssc;
  const unsigned ldsOf0 = (unsigned)tid * 16;

  // --- fragment byte-offsets: row = band + m*16 + llo, chunk = ks*4 + lhi ---
  unsigned fA[4][4], fB[4][4];
#pragma unroll
  for (int ks = 0; ks < 4; ++ks)
#pragma unroll
    for (int m = 0; m < 4; ++m) {
      int chc = ks * 4 + lhi;
      int ra  = wr * 64 + m * 16 + llo;
      fA[ks][m] = (unsigned)(ra * BK + (((unsigned)(chc ^ (ra & 7))) << 4));
      int rb  = wc * 64 + m * 16 + llo;
      fB[ks][m] = (unsigned)(rb * BK + (((unsigned)(chc ^ (rb & 7))) << 4));
    }

  v4i acc[4][4] = {};

#pragma unroll
  for (int kt = 0; kt < NK; ++kt) {
    const unsigned kb = (unsigned)kt * BK;
#pragma unroll
    for (int r = 0; r < 8; ++r) {
      GLOAD_LDS16(E8 + offA0 + r * 8192 + kb, &As[ldsOf0 + r * 4096]);
      GLOAD_LDS16(E8 + offB0 + r * 8192 + kb, &Bs[ldsOf0 + r * 4096]);
    }
    __syncthreads();   // drain: tile kt resident (1 of only 2 drains/block)
#pragma unroll
    for (int ks = 0; ks < 4; ++ks) {
      v4i af[4], bf[4];
#pragma unroll
      for (int m = 0; m < 4; ++m) {
        af[m] = *(const v4i*)&As[fA[ks][m]];
        bf[m] = *(const v4i*)&Bs[fB[ks][m]];
      }
#pragma unroll
      for (int m = 0; m < 4; ++m)
#pragma unroll
        for (int n = 0; n < 4; ++n)
          acc[m][n] = __builtin_amdgcn_mfma_i32_16x16x64_i8(af[m], bf[n],
                                                            acc[m][n], 0, 0, 0);
    }
    if (kt + 1 < NK) __syncthreads();   // protect LDS before restage
  }

  // --- epilogue (R13/R17-verified): exp, partials, single-writer P stores ---
  // C/D layout: col = lane&15, row = (lane>>4)*4 + reg
  float* __restrict__ Prow = P + ((size_t)ti * 2 * NTILE + (size_t)tj * 2 + wc) * BM;
  float* __restrict__ Pcol = P + ((size_t)tj * 2 * NTILE + (size_t)ti * 2 + wr) * BM;
  float cs[4] = {0.f, 0.f, 0.f, 0.f};
#pragma unroll
  for (int m = 0; m < 4; ++m) {
    float rs[4] = {0.f, 0.f, 0.f, 0.f};
#pragma unroll
    for (int n = 0; n < 4; ++n) {
      int gc = colTile + wc * 64 + n * 16 + llo;
#pragma unroll
      for (int jj = 0; jj < 4; ++jj) {
        int gr = rowTile + wr * 64 + m * 16 + lhi * 4 + jj;
        float s = (float)acc[m][n][jj] * SCL;
        if (posT && gc - gr == B_) pos[gr] = s;   // unique writer
        float e = __expf(s);
        e = (diag && gr == gc) ? 0.0f : e;
        rs[jj] += e;
        cs[n]  += e;
      }
    }
#pragma unroll
    for (int jj = 0; jj < 4; ++jj) {
      float v = rs[jj];
      v += __shfl_xor(v, 1);
      v += __shfl_xor(v, 2);
      v += __shfl_xor(v, 4);
      v += __shfl_xor(v, 8);
      if (llo == 0) Prow[wr * 64 + m * 16 + lhi * 4 + jj] = v;  // slot tj*2+wc
    }
  }
  if (!diag) {
    // column sums = row sums of mirrored tile (j,i)
#pragma unroll
    for (int n = 0; n < 4; ++n) {
      float v = cs[n];
      v += __shfl_xor(v, 16);
      v += __shfl_xor(v, 32);
      if (lhi == 0) Pcol[wc * 64 + n * 16 + llo] = v;           // slot ti*2+wr
    }
  }
}

// ---------------------------------------------------------------------------
// Kernel 3: gather L[r] = sum over 128 slots of P[ti][j2][rloc];
// nll = log(L) - pos; per-block partial -> par[32].
// ---------------------------------------------------------------------------
__global__ void ntx_fin1(const float* __restrict__ P, const float* __restrict__ pos,
                         float* __restrict__ par) {
  int r = blockIdx.x * 256 + threadIdx.x;     // 32 blocks x 256 rows
  int ti = r >> 7, rloc = r & 127;
  const float* base = P + (size_t)ti * 2 * NTILE * BM + rloc;
  float s = 0.f;
#pragma unroll 16
  for (int j = 0; j < 2 * NTILE; ++j) s += base[j * BM];
  float nll = __logf(s) - pos[r & (B_ - 1)];
  float v = nll;
#pragma unroll
  for (int off = 1; off < 64; off <<= 1) v += __shfl_xor(v, off);
  __shared__ float sm[4];
  if ((threadIdx.x & 63) == 0) sm[threadIdx.x >> 6] = v;
  __syncthreads();
  if (threadIdx.x == 0) par[blockIdx.x] = sm[0] + sm[1] + sm[2] + sm[3];
}

// Kernel 4: fold 32 partials -> mean
__global__ void ntx_fin2(const float* __restrict__ par, float* __restrict__ out) {
  int t = threadIdx.x;                         // 64 threads
  float s = (t < 32) ? par[t] : 0.f;
#pragma unroll
  for (int off = 1; off < 32; off <<= 1) s += __shfl_xor(s, off);
  if (t == 0) out[0] = s * (1.0f / TB_);
}

// ---------------------------------------------------------------------------
extern "C" void kernel_launch(void* const* d_in, const int* in_sizes, int n_in,
                              void* d_out, int out_size, void* d_ws, size_t ws_size,
                              hipStream_t stream) {
  const float* e1 = (const float*)d_in[0];
  const float* e2 = (const float*)d_in[1];
  float* out = (float*)d_out;
  char*  E8  = (char*)d_ws;                                       // 4 MB i8
  float* P   = (float*)((char*)d_ws + (size_t)TB_ * D_);          // 4 MB partials
  float* pos = P + (size_t)NTILE * 2 * NTILE * BM;                // 16 KB
  float* par = pos + B_;                                          // 128 B

  ntx_prep<<<1024, 256, 0, stream>>>(e1, e2, E8);
  ntx_sim<<<NTRI, 256, 0, stream>>>(E8, P, pos);
  ntx_fin1<<<TB_ / 256, 256, 0, stream>>>(P, pos, par);
  ntx_fin2<<<1, 64, 0, stream>>>(par, out);
}

// Round 21
// 57.949 us; speedup vs baseline: 1.0523x; 1.0523x over previous
//
#include <hip/hip_runtime.h>
#include <hip/hip_bf16.h>

#define B_    4096
#define D_    512         // elements = bytes per row (i8)
#define TB_   8192        // 2B rows
#define BM    128
#define BK    128         // 128 B per row per K-tile (0-conflict geometry)
#define NK    4           // D_/BK
#define NTILE 64          // TB_/BM
#define NTRI  2080        // triangular tiles
#define NPERS 520         // persistent blocks = 8*65 (XCD-bijective), 4 tiles each
#define INV_T 14.285714285714286f   // 1/0.07
#define SCL   (INV_T / 16129.0f)    // 1/(0.07*127*127)

typedef __attribute__((ext_vector_type(4))) int v4i;

#define GLOAD_LDS16(gp, lp)                                                        \
  __builtin_amdgcn_global_load_lds((const __attribute__((address_space(1))) void*)(gp), \
                                   (__attribute__((address_space(3))) void*)(lp),  \
                                   16, 0, 0)

// ---------------------------------------------------------------------------
// Kernel 1: concat + quantize fp32 -> int8 (E8[8192][512], q = rn(127 x)).
// ---------------------------------------------------------------------------
__global__ void ntx_prep(const float* __restrict__ a, const float* __restrict__ b,
                         char* __restrict__ E8) {
  int t = blockIdx.x * blockDim.x + threadIdx.x;      // 0..262143
  int i = t * 16;
  const float* src = (i < B_ * D_) ? (a + i) : (b + (i - B_ * D_));
  v4i o;
#pragma unroll
  for (int g = 0; g < 4; ++g) {
    float4 v = ((const float4*)src)[g];
    int q0 = __float2int_rn(v.x * 127.0f) & 255;
    int q1 = __float2int_rn(v.y * 127.0f) & 255;
    int q2 = __float2int_rn(v.z * 127.0f) & 255;
    int q3 = __float2int_rn(v.w * 127.0f) & 255;
    o[g] = q0 | (q1 << 8) | (q2 << 16) | (q3 << 24);
  }
  ((v4i*)E8)[t] = o;
}

// ---------------------------------------------------------------------------
// Kernel 2: PERSISTENT 4-tile blocks on R17's verbatim tile structure.
// Per tile: R17's 2-barrier kt loop, but raw s_barrier (no vmcnt drain at
// the consumption barrier — safe: each wave's ds_reads are lgkmcnt-drained
// before its MFMAs, hence before it reaches the barrier) and the next
// stage issued right after it. At kt=3 the NEXT TILE's kt=0 stage is
// issued, then the register-only epilogue (exp + shuffle reduce + P
// stores, >=1000 cyc) runs while it flies -> tile-boundary drain hidden.
// 520 blocks x 4 consecutive triangular tiles (same-ti runs -> L2 reuse).
// Swizzle/frag algebra/P-slot scheme byte-identical to R17 (passed).
// ---------------------------------------------------------------------------
__global__ __launch_bounds__(256, 2)
void ntx_sim(const char* __restrict__ E8, float* __restrict__ P,
             float* __restrict__ pos) {
  __shared__ __align__(16) char As[BM * BK];   // 16 KB
  __shared__ __align__(16) char Bs[BM * BK];   // 16 KB

  // XCD-contiguous bijective block swizzle (520 = 8*65)
  const int bid = blockIdx.x;
  const int pb  = (bid & 7) * (NPERS / 8) + (bid >> 3);
  const int t0  = pb * 4;
  // decode triangular index t0 -> (ti, tj), ti<=tj
  int ti = (int)((129.0f - sqrtf(16641.0f - 8.0f * (float)t0)) * 0.5f);
  while (ti * (129 - ti) / 2 > t0) --ti;
  while ((ti + 1) * (128 - ti) / 2 <= t0) ++ti;
  int tj = ti + (t0 - ti * (129 - ti) / 2);

  const int tid = threadIdx.x, lane = tid & 63, wave = tid >> 6;
  const int wr = wave >> 1, wc = wave & 1;
  const int llo = lane & 15, lhi = lane >> 4;

  // staging bases (R17 diet): round r adds r*16384 global / r*4096 LDS
  const int srow = tid >> 3;
  const int ssc  = ((tid & 7) ^ (srow & 7)) << 4;
  const unsigned ldsOf0 = (unsigned)tid * 16;
  // fragment bases (R17 algebra): f[ks][m] = base ^ (ks*64) + m*2048
  const unsigned baseA = (unsigned)((wr * 64 + llo) * BK + ((lhi ^ (llo & 7)) << 4));
  const unsigned baseB = (unsigned)((wc * 64 + llo) * BK + ((lhi ^ (llo & 7)) << 4));

  unsigned offA0 = (unsigned)(ti * BM + srow) * D_ + ssc;
  unsigned offB0 = (unsigned)(tj * BM + srow) * D_ + ssc;

  // prologue: stage (tile 0, kt 0)
#pragma unroll
  for (int r = 0; r < 4; ++r) {
    GLOAD_LDS16(E8 + offA0 + r * 16384, &As[ldsOf0 + r * 4096]);
    GLOAD_LDS16(E8 + offB0 + r * 16384, &Bs[ldsOf0 + r * 4096]);
  }

  for (int it = 0; it < 4; ++it) {
    const int rowTile = ti * BM, colTile = tj * BM;
    const bool diag = (ti == tj);
    const bool posT = (tj == ti + B_ / BM);
    // next tile (triangular order)
    int nti = ti, ntj = tj + 1;
    if (ntj == NTILE) { nti = ti + 1; ntj = nti; }
    const unsigned offA0n = (unsigned)(nti * BM + srow) * D_ + ssc;
    const unsigned offB0n = (unsigned)(ntj * BM + srow) * D_ + ssc;

    v4i acc[4][4] = {};

#pragma unroll
    for (int kt = 0; kt < NK; ++kt) {
      asm volatile("s_waitcnt vmcnt(0)" ::: "memory");  // own stage landed
      __builtin_amdgcn_s_barrier();                     // all waves' stage done
#pragma unroll
      for (int ks = 0; ks < 2; ++ks) {
        const unsigned bA = baseA ^ (ks * 64);
        const unsigned bB = baseB ^ (ks * 64);
        v4i af[4], bf[4];
#pragma unroll
        for (int m = 0; m < 4; ++m) {
          af[m] = *(const v4i*)&As[bA + m * 2048];
          bf[m] = *(const v4i*)&Bs[bB + m * 2048];
        }
#pragma unroll
        for (int m = 0; m < 4; ++m)
#pragma unroll
          for (int n = 0; n < 4; ++n)
            acc[m][n] = __builtin_amdgcn_mfma_i32_16x16x64_i8(af[m], bf[n],
                                                              acc[m][n], 0, 0, 0);
      }
      __builtin_amdgcn_s_barrier();   // all waves consumed buffer (reads drained
                                      // by lgkmcnt before their MFMAs)
      if (kt + 1 < NK) {
        const unsigned kb = (unsigned)(kt + 1) * BK;
#pragma unroll
        for (int r = 0; r < 4; ++r) {
          GLOAD_LDS16(E8 + offA0 + r * 16384 + kb, &As[ldsOf0 + r * 4096]);
          GLOAD_LDS16(E8 + offB0 + r * 16384 + kb, &Bs[ldsOf0 + r * 4096]);
        }
      } else if (it + 1 < 4) {
        // tile-boundary stage: flies during the epilogue below
#pragma unroll
        for (int r = 0; r < 4; ++r) {
          GLOAD_LDS16(E8 + offA0n + r * 16384, &As[ldsOf0 + r * 4096]);
          GLOAD_LDS16(E8 + offB0n + r * 16384, &Bs[ldsOf0 + r * 4096]);
        }
      }
    }

    // --- epilogue (R13/R17-verified): exp, partials, single-writer stores ---
    // C/D layout: col = lane&15, row = (lane>>4)*4 + reg
    float* __restrict__ Prow = P + ((size_t)ti * 2 * NTILE + (size_t)tj * 2 + wc) * BM;
    float* __restrict__ Pcol = P + ((size_t)tj * 2 * NTILE + (size_t)ti * 2 + wr) * BM;
    float cs[4] = {0.f, 0.f, 0.f, 0.f};
#pragma unroll
    for (int m = 0; m < 4; ++m) {
      float rs[4] = {0.f, 0.f, 0.f, 0.f};
#pragma unroll
      for (int n = 0; n < 4; ++n) {
        int gc = colTile + wc * 64 + n * 16 + llo;
#pragma unroll
        for (int jj = 0; jj < 4; ++jj) {
          int gr = rowTile + wr * 64 + m * 16 + lhi * 4 + jj;
          float s = (float)acc[m][n][jj] * SCL;
          if (posT && gc - gr == B_) pos[gr] = s;   // unique writer
          float e = __expf(s);
          e = (diag && gr == gc) ? 0.0f : e;
          rs[jj] += e;
          cs[n]  += e;
        }
      }
#pragma unroll
      for (int jj = 0; jj < 4; ++jj) {
        float v = rs[jj];
        v += __shfl_xor(v, 1);
        v += __shfl_xor(v, 2);
        v += __shfl_xor(v, 4);
        v += __shfl_xor(v, 8);
        if (llo == 0) Prow[wr * 64 + m * 16 + lhi * 4 + jj] = v;  // slot tj*2+wc
      }
    }
    if (!diag) {
#pragma unroll
      for (int n = 0; n < 4; ++n) {
        float v = cs[n];
        v += __shfl_xor(v, 16);
        v += __shfl_xor(v, 32);
        if (lhi == 0) Pcol[wc * 64 + n * 16 + llo] = v;           // slot ti*2+wr
      }
    }

    ti = nti; tj = ntj;
    offA0 = offA0n; offB0 = offB0n;
  }
}

// ---------------------------------------------------------------------------
// Kernel 3: gather L[r] = sum over 128 slots of P[ti][j2][rloc];
// nll = log(L) - pos; per-block partial -> par[32].
// ---------------------------------------------------------------------------
__global__ void ntx_fin1(const float* __restrict__ P, const float* __restrict__ pos,
                         float* __restrict__ par) {
  int r = blockIdx.x * 256 + threadIdx.x;     // 32 blocks x 256 rows
  int ti = r >> 7, rloc = r & 127;
  const float* base = P + (size_t)ti * 2 * NTILE * BM + rloc;
  float s = 0.f;
#pragma unroll 16
  for (int j = 0; j < 2 * NTILE; ++j) s += base[j * BM];
  float nll = __logf(s) - pos[r & (B_ - 1)];
  float v = nll;
#pragma unroll
  for (int off = 1; off < 64; off <<= 1) v += __shfl_xor(v, off);
  __shared__ float sm[4];
  if ((threadIdx.x & 63) == 0) sm[threadIdx.x >> 6] = v;
  __syncthreads();
  if (threadIdx.x == 0) par[blockIdx.x] = sm[0] + sm[1] + sm[2] + sm[3];
}

// Kernel 4: fold 32 partials -> mean
__global__ void ntx_fin2(const float* __restrict__ par, float* __restrict__ out) {
  int t = threadIdx.x;                         // 64 threads
  float s = (t < 32) ? par[t] : 0.f;
#pragma unroll
  for (int off = 1; off < 32; off <<= 1) s += __shfl_xor(s, off);
  if (t == 0) out[0] = s * (1.0f / TB_);
}

// ---------------------------------------------------------------------------
extern "C" void kernel_launch(void* const* d_in, const int* in_sizes, int n_in,
                              void* d_out, int out_size, void* d_ws, size_t ws_size,
                              hipStream_t stream) {
  const float* e1 = (const float*)d_in[0];
  const float* e2 = (const float*)d_in[1];
  float* out = (float*)d_out;
  char*  E8  = (char*)d_ws;                                       // 4 MB i8
  float* P   = (float*)((char*)d_ws + (size_t)TB_ * D_);          // 4 MB partials
  float* pos = P + (size_t)NTILE * 2 * NTILE * BM;                // 16 KB
  float* par = pos + B_;                                          // 128 B

  ntx_prep<<<1024, 256, 0, stream>>>(e1, e2, E8);
  ntx_sim<<<NPERS, 256, 0, stream>>>(E8, P, pos);
  ntx_fin1<<<TB_ / 256, 256, 0, stream>>>(P, pos, par);
  ntx_fin2<<<1, 64, 0, stream>>>(par, out);
}

// Round 22
// 50.190 us; speedup vs baseline: 1.2150x; 1.1546x over previous
//
#include <hip/hip_runtime.h>
#include <hip/hip_bf16.h>

#define B_    4096
#define D_    512         // elements = bytes per row (i8)
#define TB_   8192        // 2B rows
#define BM    128
#define BK    128         // 128 B per row per K-tile (0-conflict geometry)
#define NK    4           // D_/BK
#define NTILE 64          // TB_/BM
#define NTRI  2080        // NTILE*(NTILE+1)/2 = 8*260 (XCD-bijective)
#define INV_T 14.285714285714286f   // 1/0.07
#define SCL   (INV_T / 16129.0f)    // 1/(0.07*127*127)

typedef __attribute__((ext_vector_type(4))) int v4i;

#define GLOAD_LDS16(gp, lp)                                                        \
  __builtin_amdgcn_global_load_lds((const __attribute__((address_space(1))) void*)(gp), \
                                   (__attribute__((address_space(3))) void*)(lp),  \
                                   16, 0, 0)

// ---------------------------------------------------------------------------
// Kernel 1: concat + quantize fp32 -> int8 (E8[8192][512], q = rn(127 x)).
// ---------------------------------------------------------------------------
__global__ void ntx_prep(const float* __restrict__ a, const float* __restrict__ b,
                         char* __restrict__ E8) {
  int t = blockIdx.x * blockDim.x + threadIdx.x;      // 0..262143
  int i = t * 16;
  const float* src = (i < B_ * D_) ? (a + i) : (b + (i - B_ * D_));
  v4i o;
#pragma unroll
  for (int g = 0; g < 4; ++g) {
    float4 v = ((const float4*)src)[g];
    int q0 = __float2int_rn(v.x * 127.0f) & 255;
    int q1 = __float2int_rn(v.y * 127.0f) & 255;
    int q2 = __float2int_rn(v.z * 127.0f) & 255;
    int q3 = __float2int_rn(v.w * 127.0f) & 255;
    o[g] = q0 | (q1 << 8) | (q2 << 16) | (q3 << 24);
  }
  ((v4i*)E8)[t] = o;
}

// ---------------------------------------------------------------------------
// Kernel 2: measured-best sim (R17, 50.08 us total). i8 GEMM, 128x128 tile,
// 4 waves of 64x64, BK=128, simple 2-barrier loop (every pipelining /
// occupancy / operand-path restructuring measured worse: R3-R21).
// Triangular tiles (sim symmetric) + mirror col-sums; XCD-bijective block
// swizzle; chunk-XOR LDS swizzle (chunk ^= row&7) on BOTH the pre-swizzled
// global source and the ds_read (0 bank conflicts); atomic-free epilogue
// (single-writer P slots: R12's ln2 lesson); pos extracted from tiles
// tj == ti + 32; register-dieted addressing (R17 algebra).
// ---------------------------------------------------------------------------
__global__ __launch_bounds__(256, 4)
void ntx_sim(const char* __restrict__ E8, float* __restrict__ P,
             float* __restrict__ pos) {
  __shared__ __align__(16) char As[BM * BK];   // 16 KB
  __shared__ __align__(16) char Bs[BM * BK];   // 16 KB

  // XCD-contiguous bijective swizzle (2080 = 8*260)
  const int bid = blockIdx.x;
  const int t   = (bid & 7) * (NTRI / 8) + (bid >> 3);
  // decode triangular index t -> (ti, tj), ti<=tj
  int ti = (int)((129.0f - sqrtf(16641.0f - 8.0f * (float)t)) * 0.5f);
  while (ti * (129 - ti) / 2 > t) --ti;
  while ((ti + 1) * (128 - ti) / 2 <= t) ++ti;
  const int tj = ti + (t - ti * (129 - ti) / 2);
  const int rowTile = ti * BM, colTile = tj * BM;
  const bool diag = (ti == tj);
  const bool posT = (tj == ti + B_ / BM);   // holds s[r][r+B] on local diag

  const int tid = threadIdx.x, lane = tid & 63, wave = tid >> 6;
  const int wr = wave >> 1, wc = wave & 1;
  const int llo = lane & 15, lhi = lane >> 4;

  // --- staging bases (round r adds r*16384 global / r*4096 LDS) ---
  const int srow = tid >> 3;
  const int ssc  = ((tid & 7) ^ (srow & 7)) << 4;
  const unsigned offA0  = (unsigned)(rowTile + srow) * D_ + ssc;
  const unsigned offB0  = (unsigned)(colTile + srow) * D_ + ssc;
  const unsigned ldsOf0 = (unsigned)tid * 16;

  // --- fragment bases: f[ks][m] = base ^ (ks*64) + m*2048 ---
  const unsigned baseA = (unsigned)((wr * 64 + llo) * BK + ((lhi ^ (llo & 7)) << 4));
  const unsigned baseB = (unsigned)((wc * 64 + llo) * BK + ((lhi ^ (llo & 7)) << 4));

  v4i acc[4][4] = {};

  for (int kt = 0; kt < NK; ++kt) {
    const unsigned kb = (unsigned)kt * BK;
#pragma unroll
    for (int r = 0; r < 4; ++r) {
      GLOAD_LDS16(E8 + offA0 + r * 16384 + kb, &As[ldsOf0 + r * 4096]);
      GLOAD_LDS16(E8 + offB0 + r * 16384 + kb, &Bs[ldsOf0 + r * 4096]);
    }
    __syncthreads();   // drains vmcnt: tile resident
#pragma unroll
    for (int ks = 0; ks < 2; ++ks) {
      const unsigned bA = baseA ^ (ks * 64);
      const unsigned bB = baseB ^ (ks * 64);
      v4i af[4], bf[4];
#pragma unroll
      for (int m = 0; m < 4; ++m) {
        af[m] = *(const v4i*)&As[bA + m * 2048];
        bf[m] = *(const v4i*)&Bs[bB + m * 2048];
      }
#pragma unroll
      for (int m = 0; m < 4; ++m)
#pragma unroll
        for (int n = 0; n < 4; ++n)
          acc[m][n] = __builtin_amdgcn_mfma_i32_16x16x64_i8(af[m], bf[n],
                                                            acc[m][n], 0, 0, 0);
    }
    __syncthreads();   // protect LDS before next staging
  }

  // --- epilogue: exp, partials, single-writer P stores ---
  // C/D layout: col = lane&15, row = (lane>>4)*4 + reg
  float* __restrict__ Prow = P + ((size_t)ti * 2 * NTILE + (size_t)tj * 2 + wc) * BM;
  float* __restrict__ Pcol = P + ((size_t)tj * 2 * NTILE + (size_t)ti * 2 + wr) * BM;
  float cs[4] = {0.f, 0.f, 0.f, 0.f};
#pragma unroll
  for (int m = 0; m < 4; ++m) {
    float rs[4] = {0.f, 0.f, 0.f, 0.f};
#pragma unroll
    for (int n = 0; n < 4; ++n) {
      int gc = colTile + wc * 64 + n * 16 + llo;
#pragma unroll
      for (int jj = 0; jj < 4; ++jj) {
        int gr = rowTile + wr * 64 + m * 16 + lhi * 4 + jj;
        float s = (float)acc[m][n][jj] * SCL;
        if (posT && gc - gr == B_) pos[gr] = s;   // unique writer
        float e = __expf(s);
        e = (diag && gr == gc) ? 0.0f : e;
        rs[jj] += e;
        cs[n]  += e;
      }
    }
#pragma unroll
    for (int jj = 0; jj < 4; ++jj) {
      float v = rs[jj];
      v += __shfl_xor(v, 1);
      v += __shfl_xor(v, 2);
      v += __shfl_xor(v, 4);
      v += __shfl_xor(v, 8);
      if (llo == 0) Prow[wr * 64 + m * 16 + lhi * 4 + jj] = v;  // slot tj*2+wc
    }
  }
  if (!diag) {
    // column sums = row sums of mirrored tile (j,i)
#pragma unroll
    for (int n = 0; n < 4; ++n) {
      float v = cs[n];
      v += __shfl_xor(v, 16);
      v += __shfl_xor(v, 32);
      if (lhi == 0) Pcol[wc * 64 + n * 16 + llo] = v;           // slot ti*2+wr
    }
  }
}

// ---------------------------------------------------------------------------
// Kernel 3: gather L[r] = sum over 128 slots of P[ti][j2][rloc];
// nll = log(L) - pos; per-block partial -> par[32].
// ---------------------------------------------------------------------------
__global__ void ntx_fin1(const float* __restrict__ P, const float* __restrict__ pos,
                         float* __restrict__ par) {
  int r = blockIdx.x * 256 + threadIdx.x;     // 32 blocks x 256 rows
  int ti = r >> 7, rloc = r & 127;
  const float* base = P + (size_t)ti * 2 * NTILE * BM + rloc;
  float s = 0.f;
#pragma unroll 16
  for (int j = 0; j < 2 * NTILE; ++j) s += base[j * BM];
  float nll = __logf(s) - pos[r & (B_ - 1)];
  float v = nll;
#pragma unroll
  for (int off = 1; off < 64; off <<= 1) v += __shfl_xor(v, off);
  __shared__ float sm[4];
  if ((threadIdx.x & 63) == 0) sm[threadIdx.x >> 6] = v;
  __syncthreads();
  if (threadIdx.x == 0) par[blockIdx.x] = sm[0] + sm[1] + sm[2] + sm[3];
}

// Kernel 4: fold 32 partials -> mean
__global__ void ntx_fin2(const float* __restrict__ par, float* __restrict__ out) {
  int t = threadIdx.x;                         // 64 threads
  float s = (t < 32) ? par[t] : 0.f;
#pragma unroll
  for (int off = 1; off < 32; off <<= 1) s += __shfl_xor(s, off);
  if (t == 0) out[0] = s * (1.0f / TB_);
}

// ---------------------------------------------------------------------------
extern "C" void kernel_launch(void* const* d_in, const int* in_sizes, int n_in,
                              void* d_out, int out_size, void* d_ws, size_t ws_size,
                              hipStream_t stream) {
  const float* e1 = (const float*)d_in[0];
  const float* e2 = (const float*)d_in[1];
  float* out = (float*)d_out;
  char*  E8  = (char*)d_ws;                                       // 4 MB i8
  float* P   = (float*)((char*)d_ws + (size_t)TB_ * D_);          // 4 MB partials
  float* pos = P + (size_t)NTILE * 2 * NTILE * BM;                // 16 KB
  float* par = pos + B_;                                          // 128 B

  ntx_prep<<<1024, 256, 0, stream>>>(e1, e2, E8);
  ntx_sim<<<NTRI, 256, 0, stream>>>(E8, P, pos);
  ntx_fin1<<<TB_ / 256, 256, 0, stream>>>(P, pos, par);
  ntx_fin2<<<1, 64, 0, stream>>>(par, out);
}